// Round 13
// baseline (111.890 us; speedup 1.0000x reference)
//
#include <hip/hip_runtime.h>
#include <hip/hip_fp8.h>
#include <math.h>

// XYSearcher, sliding-window banded-GEMM, 32x32x16 FP8 MFMA,
// producer/consumer wave specialization + K-SPLIT dual consumer teams.
//   ||q_a - p_b||^2 = ||q_a||^2 + ||p_b||^2 - 2 q_a.p_b
// Integer steps: step k pairs rows at delta = a-b = +(k+1) [pos] / -(k+1)
// [neg]; one wrapped corner pair per step (fused corner blocks, exact fp32).
// Norms exact fp32; cross-term fp8 e4m3 (absmax 0 verified round 12).
// 14 waves: 0-4 lo-K consumers (MFMA k-steps 0..7), 5-8 producers (code and
// protocol constants identical to verified round 12), 9-13 hi-K consumers
// (k-steps 8..15). Hi team writes partial dot (16 f32/lane) to double-
// buffered LDS scratch; lo team adds it in the verified epilogue.
// Rationale: all pipes <30% busy and warm replays (0.24MB fetch) as slow as
// cold (115MB) -> stall-bound at 2.25 waves/SIMD. 14 waves = 3.5/SIMD in ONE
// block (no multi-block co-residency bet; round 12 showed it doesn't engage).
// Protocol (round-12 verified): producer round j stages P[T0+j-2]->slot j%6,
// (j>=4) Q[T0+j-4]->slot (j-4)&1, rounds j=0..ns+3. Consumer iter s needs
// prod fields >= s+5. Producer round j needs BOTH consumer teams >= j-5.
// Handoff: hi signals packs[3] after scratch write (iter s -> count s+1);
// lo waits >= s+1. Scratch rewrite: hi at iter s>=2 waits lo >= s-1 (dbuf).
// LDS stride 296B = 74 dwords = 10 mod 32 -> 2-way max (free), fixing round
// 12's 4-way conflicts (stride 272).

typedef __attribute__((ext_vector_type(16))) float f32x16;

#define LDSB 296                 // bytes per LDS row (256 fp8 + 40 pad)
#define TILEB (32 * LDSB)        // 9472 B per 32-row tile
#define PR 6                     // P ring slots (5-tile window + 1 incoming)
#define MAXS 128
#define NREP 32
#define SCRW 18                  // scratch floats per lane (16 + 2 pad)

#define LGKM_FENCE()                                                          \
  do {                                                                        \
    __builtin_amdgcn_sched_barrier(0);                                        \
    asm volatile("s_waitcnt lgkmcnt(0)" ::: "memory");                        \
    __builtin_amdgcn_sched_barrier(0);                                        \
  } while (0)

__device__ __forceinline__ unsigned char f2fp8(float x) {
  __hip_fp8_e4m3 v(x);
  return (unsigned char)v.__x;
}

// Bijective XCD-chunked remap (m204): 8 XCDs, contiguous chunk per XCD.
__device__ __forceinline__ int xcd_swz(int bid, int nwg) {
  const int q = nwg >> 3, r = nwg & 7;
  const int x = bid & 7, i = bid >> 3;
  return (x < r ? x * (q + 1) : r * (q + 1) + (x - r) * q) + i;
}

__global__ __launch_bounds__(896, 1)
void band_kernel(const float* __restrict__ Q, const float* __restrict__ P,
                 double* __restrict__ ws,
                 const int* __restrict__ msp, const int* __restrict__ ssp,
                 int N, int TS, int gridB) {
  __shared__ __align__(16) unsigned char Bsh[PR * TILEB];   // 56832 B
  __shared__ __align__(16) unsigned char Qsh[2 * TILEB];    // 18944 B
  __shared__ float scr[2][5][64 * SCRW];                    // 46080 B
  __shared__ float NpS[PR * 32];
  __shared__ float NqS[2 * 32];
  __shared__ float sums[MAXS];
  __shared__ float red[14];
  __shared__ int packs[4];  // [0] prod 4x8b, [1] cons-lo 5x6b, [2] cons-hi 5x6b, [3] handoff 5x6b

  const int t = threadIdx.x;
  const int lane = t & 63;
  const int wid = t >> 6;          // 0..13
  const int ms = msp[0], ss = ssp[0];
  const int S1 = (ms + ss - 1) / ss;
  const int S = 2 * S1;

  // ---------------- fused corner blocks: one wrapped pair per step ---------
  if (blockIdx.x >= gridB) {
    const int si = blockIdx.x - gridB;
    if (si >= S) return;
    int k, qr, pr;
    if (si < S1) { k = si * ss;            qr = 0;           pr = N - (k + 1); }
    else         { k = 1 + (si - S1) * ss; qr = N - (k + 1); pr = 0; }
    float sq = 0.f;
    if (t < 256) {
      const float e = Q[(size_t)qr * 256 + t] - P[(size_t)pr * 256 + t];
      sq = e * e;
    }
    #pragma unroll
    for (int off = 32; off >= 1; off >>= 1) sq += __shfl_xor(sq, off);
    if (lane == 0) red[wid] = sq;
    __syncthreads();
    if (t == 0) {
      float tot = 0.f;
      #pragma unroll
      for (int w = 0; w < 14; ++w) tot += red[w];
      ws[(size_t)NREP * MAXS + si] = (double)sqrtf(tot);
    }
    return;
  }

  // ---------------- band blocks -------------------------------------------
  const int sb = xcd_swz(blockIdx.x, gridB);   // swizzled strip id
  const int T0 = (int)(((long long)sb * TS) / gridB);
  const int T1 = (int)(((long long)(sb + 1) * TS) / gridB);
  const int ns = T1 - T0;                      // ~12-13 subtiles per strip
  if (ns <= 0) return;

  for (int i = t; i < MAXS; i += 896) sums[i] = 0.f;
  if (t == 0) { packs[0] = 0; packs[1] = 0; packs[2] = 0; packs[3] = 0; }
  __syncthreads();

  volatile int* vprod = &packs[0];
  volatile int* vlo   = &packs[1];
  volatile int* vhi   = &packs[2];
  volatile int* vhand = &packs[3];

  if (wid >= 5 && wid <= 8) {
    // ================= PRODUCER waves (5..8) — round-12 verified ==========
    const int pw = wid - 5;              // 0..3: rows pw*8 .. pw*8+7 per tile
    const int rr = pw * 8 + (lane >> 3); // tile-local row 0..31
    const int li = lane & 7;             // 8 lanes/row; cols li*8+j*64, 8 each

    auto issueT = [&](const float* __restrict__ base, int tau, float4* v) {
      const int gr = tau * 32 + rr;
      if (gr >= 0 && gr < N) {
        const float* src = base + (size_t)gr * 256 + li * 8;
        #pragma unroll
        for (int j = 0; j < 4; ++j) {
          v[2 * j]     = *reinterpret_cast<const float4*>(src + j * 64);
          v[2 * j + 1] = *reinterpret_cast<const float4*>(src + j * 64 + 4);
        }
      } else {
        #pragma unroll
        for (int j = 0; j < 8; ++j) v[j] = make_float4(0.f, 0.f, 0.f, 0.f);
      }
    };

    auto commitT = [&](unsigned char* dst, float* ndst, int slot, const float4* v) {
      float nrm = 0.f;
      unsigned char* row = dst + slot * TILEB + rr * LDSB + li * 8;
      #pragma unroll
      for (int j = 0; j < 4; ++j) {
        const float f0 = v[2*j].x, f1 = v[2*j].y, f2 = v[2*j].z, f3 = v[2*j].w;
        const float f4 = v[2*j+1].x, f5 = v[2*j+1].y, f6 = v[2*j+1].z, f7 = v[2*j+1].w;
        nrm = fmaf(f0, f0, nrm); nrm = fmaf(f1, f1, nrm);
        nrm = fmaf(f2, f2, nrm); nrm = fmaf(f3, f3, nrm);
        nrm = fmaf(f4, f4, nrm); nrm = fmaf(f5, f5, nrm);
        nrm = fmaf(f6, f6, nrm); nrm = fmaf(f7, f7, nrm);
        unsigned long long u =
            (unsigned long long)f2fp8(f0)
          | ((unsigned long long)f2fp8(f1) << 8)
          | ((unsigned long long)f2fp8(f2) << 16)
          | ((unsigned long long)f2fp8(f3) << 24)
          | ((unsigned long long)f2fp8(f4) << 32)
          | ((unsigned long long)f2fp8(f5) << 40)
          | ((unsigned long long)f2fp8(f6) << 48)
          | ((unsigned long long)f2fp8(f7) << 56);
        *reinterpret_cast<unsigned long long*>(row + j * 64) = u;
      }
      nrm += __shfl_xor(nrm, 1);
      nrm += __shfl_xor(nrm, 2);
      nrm += __shfl_xor(nrm, 4);
      if (li == 0) ndst[slot * 32 + rr] = nrm;   // exact fp32 row norm
    };

    float4 Ap[8], Aq[8], Bp[8], Bq[8];
    const int JT = ns + 4;               // rounds 0..ns+3

#define P_ISSUE(JJ, SET)                                                      \
    { const int pj_ = (JJ);                                                   \
      if (pj_ < JT) {                                                         \
        issueT(P, T0 + pj_ - 2, SET##p);                                      \
        if (pj_ >= 4) issueT(Q, T0 + pj_ - 4, SET##q);                        \
      } }
#define P_STEP(JJ, SET)                                                       \
    { const int j_ = (JJ);                                                    \
      const int needc = j_ - 5;                                               \
      if (needc > 0) {                                                        \
        for (;;) {                                                            \
          const int v1 = *vlo;                                                \
          const int v2 = *vhi;                                                \
          if ((v1 & 63) >= needc && ((v1 >> 6) & 63) >= needc &&              \
              ((v1 >> 12) & 63) >= needc && ((v1 >> 18) & 63) >= needc &&     \
              ((v1 >> 24) & 63) >= needc &&                                   \
              (v2 & 63) >= needc && ((v2 >> 6) & 63) >= needc &&              \
              ((v2 >> 12) & 63) >= needc && ((v2 >> 18) & 63) >= needc &&     \
              ((v2 >> 24) & 63) >= needc) break;                              \
          __builtin_amdgcn_s_sleep(1);                                        \
        }                                                                     \
      }                                                                       \
      commitT(Bsh, NpS, j_ % PR, SET##p);                                     \
      if (j_ >= 4) commitT(Qsh, NqS, (j_ - 4) & 1, SET##q);                   \
      LGKM_FENCE();                                                           \
      if (lane == 0) atomicAdd(&packs[0], 1 << (8 * pw));                     \
      P_ISSUE(j_ + 2, SET); }

    P_ISSUE(0, A);
    P_ISSUE(1, B);
    int j = 0;
    for (; j + 2 <= JT; j += 2) {
      P_STEP(j, A);
      P_STEP(j + 1, B);
    }
    if (j < JT) P_STEP(j, A);
#undef P_STEP
#undef P_ISSUE
  } else {
    // ================= CONSUMER waves: lo (0..4, k0-7), hi (9..13, k8-15) ==
    const int loTeam = (wid < 5);
    const int w5 = loTeam ? wid : wid - 9;   // window position 0..4
    const int l31 = lane & 31;
    const int hi = lane >> 5;

    // Per-thread step slots (T-invariant) — lo team only (does the epilogue).
    int slotR[16];
    float racc[16];
    if (loTeam) {
      #pragma unroll
      for (int r = 0; r < 16; ++r) {
        const int arow = (r & 3) + 8 * (r >> 2) + 4 * hi;
        const int d = arow - l31 - (w5 - 2) * 32;
        int slot = -1;
        if (d >= 1) {
          const int k = d - 1;
          if (k < ms && (k % ss) == 0) slot = k / ss;
        } else if (d <= -2) {
          const int kk = -d - 1;
          if (kk <= ms && ((kk - 1) % ss) == 0) slot = S1 + (kk - 1) / ss;
        }
        if (slot >= MAXS) slot = -1;
        slotR[r] = slot;
      }
      #pragma unroll
      for (int r = 0; r < 16; ++r) racc[r] = 0.f;
    }

    const int ksBase = loTeam ? 0 : 8;

    #pragma unroll 1
    for (int s = 0; s < ns; ++s) {
      const int T = T0 + s;
      const int need = s + 5;               // prod rounds 0..s+4 complete
      for (;;) {
        const int v = *vprod;
        if ((v & 255) >= need && ((v >> 8) & 255) >= need &&
            ((v >> 16) & 255) >= need && ((v >> 24) & 255) >= need) break;
        __builtin_amdgcn_s_sleep(1);
      }
      __builtin_amdgcn_sched_barrier(0);

      const int tauW = T - 2 + w5;
      const int slotP = (s + w5) % PR;
      const int slotQ = s & 1;
      const unsigned char* Ab = &Qsh[slotQ * TILEB + l31 * LDSB + hi * 8];
      const unsigned char* Bb = &Bsh[slotP * TILEB + l31 * LDSB + hi * 8];
      f32x16 acc0 = {}, acc1 = {};
      __builtin_amdgcn_s_setprio(1);
      #pragma unroll
      for (int k2 = 0; k2 < 8; k2 += 2) {
        const int ks = ksBase + k2;
        const long long a0 = *reinterpret_cast<const long long*>(Ab + ks * 16);
        const long long b0 = *reinterpret_cast<const long long*>(Bb + ks * 16);
        const long long a1 = *reinterpret_cast<const long long*>(Ab + ks * 16 + 16);
        const long long b1 = *reinterpret_cast<const long long*>(Bb + ks * 16 + 16);
        acc0 = __builtin_amdgcn_mfma_f32_32x32x16_fp8_fp8(a0, b0, acc0, 0, 0, 0);
        acc1 = __builtin_amdgcn_mfma_f32_32x32x16_fp8_fp8(a1, b1, acc1, 0, 0, 0);
      }
      __builtin_amdgcn_s_setprio(0);

      if (!loTeam) {
        // ---- hi team: deliver partial dot through dbuf scratch.
        if (s >= 2) {                       // lo consumed scr[s&1] at iter s-2
          const int needl = s - 1;
          for (;;) {
            const int v = *vlo;
            if (((v >> (6 * w5)) & 63) >= needl) break;
            __builtin_amdgcn_s_sleep(1);
          }
        }
        float* sp = &scr[s & 1][w5][lane * SCRW];
        #pragma unroll
        for (int r = 0; r < 16; r += 2) {
          float2 v2;
          v2.x = acc0[r] + acc1[r];
          v2.y = acc0[r + 1] + acc1[r + 1];
          *reinterpret_cast<float2*>(sp + r) = v2;
        }
        LGKM_FENCE();                       // scratch + frag reads retired
        if (lane == 0) {
          atomicAdd(&packs[3], 1 << (6 * w5));   // handoff
          atomicAdd(&packs[2], 1 << (6 * w5));   // tile release
        }
      } else {
        // ---- lo team: wait handoff, combine, verified epilogue.
        for (;;) {
          const int v = *vhand;
          if (((v >> (6 * w5)) & 63) >= s + 1) break;
          __builtin_amdgcn_s_sleep(1);
        }
        __builtin_amdgcn_sched_barrier(0);
        const float* sp = &scr[s & 1][w5][lane * SCRW];
        float dotp[16];
        #pragma unroll
        for (int r = 0; r < 16; r += 2) {
          const float2 v2 = *reinterpret_cast<const float2*>(sp + r);
          dotp[r] = v2.x; dotp[r + 1] = v2.y;
        }

        const int bcol = tauW * 32 + l31;
        if (bcol >= 0 && bcol < N) {
          const float npW = NpS[slotP * 32 + l31];
          const int aT = T * 32;
          #pragma unroll
          for (int r = 0; r < 16; ++r) {
            const int arow = (r & 3) + 8 * (r >> 2) + 4 * hi;
            if (slotR[r] >= 0 && (aT + arow) < N) {
              const float n2 = NqS[slotQ * 32 + arow] + npW
                               - 2.0f * (acc0[r] + acc1[r] + dotp[r]);
              racc[r] += sqrtf(fmaxf(n2, 0.f));
            }
          }
        }

        LGKM_FENCE();                       // frag + scratch reads retired
        if (lane == 0) atomicAdd(&packs[1], 1 << (6 * w5));
      }
    }

    // Once-per-block: lo team registers -> LDS step slots.
    if (loTeam) {
      #pragma unroll
      for (int r = 0; r < 16; ++r)
        if (slotR[r] >= 0 && racc[r] != 0.f) atomicAdd(&sums[slotR[r]], racc[r]);
    }
  }

  __syncthreads();
  if (t < S && t < MAXS) {
    const float v = sums[t];
    if (v != 0.f)
      unsafeAtomicAdd(&ws[(size_t)(blockIdx.x & (NREP - 1)) * MAXS + t], (double)v);
  }
}

__global__ void finalize_kernel(const double* __restrict__ ws, float* __restrict__ out,
                                const int* __restrict__ msp, const int* __restrict__ ssp,
                                int N) {
  __shared__ double dist_sh[MAXS];
  const int t = threadIdx.x;
  const int ms = msp[0], ss = ssp[0];
  const int S1 = (ms + ss - 1) / ss;
  const int S = 2 * S1;
  if (t < S && t < MAXS) {
    double tot = 0.0;
    for (int rep = 0; rep < NREP; ++rep) tot += ws[(size_t)rep * MAXS + t];
    tot += ws[(size_t)NREP * MAXS + t];   // corner pair
    const int k = (t < S1) ? t * ss : 1 + (t - S1) * ss;
    dist_sh[t] = tot / (double)(N - k);
  }
  __syncthreads();
  if (t == 0) {
    int best = 0;
    double bd = dist_sh[0];
    for (int s = 1; s < S && s < MAXS; ++s)
      if (dist_sh[s] < bd) { bd = dist_sh[s]; best = s; }
    const int k = (best < S1) ? best * ss : 1 + (best - S1) * ss;
    out[0] = (best < S1) ? (float)k : -(float)k;
    out[1] = (float)bd;
  }
}

extern "C" void kernel_launch(void* const* d_in, const int* in_sizes, int n_in,
                              void* d_out, int out_size, void* d_ws, size_t ws_size,
                              hipStream_t stream) {
  const float* Q   = (const float*)d_in[0];
  const float* P   = (const float*)d_in[1];
  const int*   msp = (const int*)d_in[2];
  const int*   ssp = (const int*)d_in[3];
  const int N = in_sizes[0] / 256;
  double* ws = (double*)d_ws;

  hipMemsetAsync(d_ws, 0, (size_t)(NREP + 1) * MAXS * sizeof(double), stream);

  const int TS = (N + 31) / 32;                 // total 32-row A-subtiles
  int gridB = 256;                              // 1 block/CU, one pass
  if (gridB > TS) gridB = TS;

  band_kernel<<<gridB + MAXS, 896, 0, stream>>>(Q, P, ws, msp, ssp,
                                                N, TS, gridB);
  finalize_kernel<<<1, 128, 0, stream>>>(ws, (float*)d_out, msp, ssp, N);
}

// Round 14
// 62.138 us; speedup vs baseline: 1.8007x; 1.8007x over previous
//
#include <hip/hip_runtime.h>
#include <math.h>

// XYSearcher, sliding-window banded-GEMM, 32x32x16 MFMA,
// PRODUCER/CONSUMER wave specialization (no per-iteration barrier).
//   ||q_a - p_b||^2 = ||q_a||^2 + ||p_b||^2 - 2 q_a.p_b
// Integer steps: step k pairs rows at delta = a-b = +(k+1) [pos] / -(k+1)
// [neg]; one wrapped corner pair per step (fused corner blocks, exact fp32).
// Dots in bf16 MFMA, norms exact fp32 (absmax 0, rounds 3-8,11).
// 9 waves: waves 0-4 consume (ds frag reads + MFMA + epilogue), waves 5-8
// produce (global loads + fp32 norms + bf16 cvt + LDS ring writes).
// Sync: packed per-wave progress counters in LDS, spin + s_sleep. Round r
// stages Q[T0+r] and P[T0+r+2]; consumer iter s needs rounds <= s
// (prod fields >= s+5 counting 4 prologue rounds); producer overwriting the
// ring slot of tile T0+r-4 (last read at iter r-2) needs cons fields >= r-1.
// This is the round-7 configuration restored verbatim: best measured 61.6us.
// Post-round-7 variants (XCD swizzle, lgkm-only fences, deeper rings, fp8,
// K-split) were all neutral/regressions/correctness failures on this part.

typedef __attribute__((ext_vector_type(8))) __bf16 bf16x8;
typedef __attribute__((ext_vector_type(16))) float f32x16;
typedef __attribute__((ext_vector_type(8))) unsigned short us8;

#define LDSH 280     // shorts per LDS row (560 B = 35 x 16B slots, conflict-free)
#define RING 6       // P ring slots
#define MAXS 128
#define NREP 32

__device__ __forceinline__ unsigned short f2bf(float x) {
  return __builtin_bit_cast(unsigned short, (__bf16)x);
}

__global__ __launch_bounds__(576, 1)
void band_kernel(const float* __restrict__ Q, const float* __restrict__ P,
                 double* __restrict__ ws,
                 const int* __restrict__ msp, const int* __restrict__ ssp,
                 int N, int TS, int nsb, int gridB) {
  __shared__ __align__(16) unsigned short Bsh[RING * 32 * LDSH];  // 105 KB
  __shared__ __align__(16) unsigned short Qsh[2 * 32 * LDSH];     // 35 KB
  __shared__ float NpS[RING * 32];
  __shared__ float NqS[2 * 32];
  __shared__ float sums[MAXS];
  __shared__ float red[12];
  __shared__ int packs[2];   // [0] prod (4 x 8-bit fields), [1] cons (5 x 6-bit)

  const int t = threadIdx.x;
  const int lane = t & 63;
  const int wid = t >> 6;          // 0..8
  const int ms = msp[0], ss = ssp[0];
  const int S1 = (ms + ss - 1) / ss;
  const int S = 2 * S1;

  // ---------------- fused corner blocks: one wrapped pair per step ---------
  if (blockIdx.x >= gridB) {
    const int si = blockIdx.x - gridB;
    if (si >= S) return;
    int k, qr, pr;
    if (si < S1) { k = si * ss;            qr = 0;           pr = N - (k + 1); }
    else         { k = 1 + (si - S1) * ss; qr = N - (k + 1); pr = 0; }
    float sq = 0.f;
    if (t < 256) {
      const float e = Q[(size_t)qr * 256 + t] - P[(size_t)pr * 256 + t];
      sq = e * e;
    }
    #pragma unroll
    for (int off = 32; off >= 1; off >>= 1) sq += __shfl_xor(sq, off);
    if (lane == 0) red[wid] = sq;
    __syncthreads();
    if (t == 0) {
      float tot = 0.f;
      #pragma unroll
      for (int w = 0; w < 9; ++w) tot += red[w];
      ws[(size_t)NREP * MAXS + si] = (double)sqrtf(tot);
    }
    return;
  }

  // ---------------- band blocks -------------------------------------------
  const int T0 = blockIdx.x * nsb;
  int ns = TS - T0; if (ns > nsb) ns = nsb;
  if (ns <= 0) return;

  for (int i = t; i < MAXS; i += 576) sums[i] = 0.f;
  if (t == 0) { packs[0] = 0; packs[1] = 0; }
  __syncthreads();

  volatile int* vprod = &packs[0];
  volatile int* vcons = &packs[1];

  if (wid >= 5) {
    // ================= PRODUCER waves (5..8) ==============================
    const int pw = wid - 5;              // 0..3: rows pw*8 .. pw*8+7 of each tile
    const int rr = pw * 8 + (lane >> 3); // tile-local row 0..31
    const int li = lane & 7;             // 8 lanes per row, 32 floats each

    float4 vp[8], vq[8];

    auto issueT = [&](const float* __restrict__ base, int tau, float4* v) {
      const int gr = tau * 32 + rr;
      if (gr >= 0 && gr < N) {
        const float* src = base + (size_t)gr * 256 + li * 8;
        #pragma unroll
        for (int j = 0; j < 4; ++j) {
          v[2 * j]     = *reinterpret_cast<const float4*>(src + j * 64);
          v[2 * j + 1] = *reinterpret_cast<const float4*>(src + j * 64 + 4);
        }
      } else {
        #pragma unroll
        for (int j = 0; j < 8; ++j) v[j] = make_float4(0.f, 0.f, 0.f, 0.f);
      }
    };

    auto commitT = [&](unsigned short* dst, float* ndst, int slot, const float4* v) {
      float nrm = 0.f;
      unsigned short* row = dst + slot * 32 * LDSH + rr * LDSH + li * 8;
      #pragma unroll
      for (int j = 0; j < 4; ++j) {
        const float f0 = v[2*j].x, f1 = v[2*j].y, f2 = v[2*j].z, f3 = v[2*j].w;
        const float f4 = v[2*j+1].x, f5 = v[2*j+1].y, f6 = v[2*j+1].z, f7 = v[2*j+1].w;
        nrm = fmaf(f0, f0, nrm); nrm = fmaf(f1, f1, nrm);
        nrm = fmaf(f2, f2, nrm); nrm = fmaf(f3, f3, nrm);
        nrm = fmaf(f4, f4, nrm); nrm = fmaf(f5, f5, nrm);
        nrm = fmaf(f6, f6, nrm); nrm = fmaf(f7, f7, nrm);
        us8 h;
        h[0] = f2bf(f0); h[1] = f2bf(f1); h[2] = f2bf(f2); h[3] = f2bf(f3);
        h[4] = f2bf(f4); h[5] = f2bf(f5); h[6] = f2bf(f6); h[7] = f2bf(f7);
        *reinterpret_cast<us8*>(row + j * 64) = h;
      }
      nrm += __shfl_xor(nrm, 1);
      nrm += __shfl_xor(nrm, 2);
      nrm += __shfl_xor(nrm, 4);
      if (li == 0) ndst[slot * 32 + rr] = nrm;   // exact fp32 row norm
    };

    #pragma unroll 1
    for (int r = -4; r < ns; ++r) {
      const int tauP = T0 + r + 2;
      const bool doQ = (r >= 0);
      issueT(P, tauP, vp);                  // loads in flight during the spin
      if (doQ) issueT(Q, T0 + r, vq);
      const int needc = r - 1;              // all consumers finished iter r-2
      if (needc > 0) {
        for (;;) {
          const int v = *vcons;
          if ((v & 63) >= needc && ((v >> 6) & 63) >= needc &&
              ((v >> 12) & 63) >= needc && ((v >> 18) & 63) >= needc &&
              ((v >> 24) & 63) >= needc) break;
          __builtin_amdgcn_s_sleep(2);
        }
      }
      commitT(Bsh, NpS, (tauP + 12) % RING, vp);
      if (doQ) commitT(Qsh, NqS, (T0 + r) & 1, vq);
      __threadfence_block();                // LDS writes visible before signal
      if (lane == 0) atomicAdd(&packs[0], 1 << (8 * pw));
    }
  } else {
    // ================= CONSUMER waves (0..4) ==============================
    const int l31 = lane & 31;
    const int hi = lane >> 5;

    // Per-thread step slots (T-invariant): delta = arow - l31 - (wid-2)*32.
    int slotR[16];
    #pragma unroll
    for (int r = 0; r < 16; ++r) {
      const int arow = (r & 3) + 8 * (r >> 2) + 4 * hi;
      const int d = arow - l31 - (wid - 2) * 32;
      int slot = -1;
      if (d >= 1) {
        const int k = d - 1;
        if (k < ms && (k % ss) == 0) slot = k / ss;
      } else if (d <= -2) {
        const int kk = -d - 1;
        if (kk <= ms && ((kk - 1) % ss) == 0) slot = S1 + (kk - 1) / ss;
      }
      if (slot >= MAXS) slot = -1;
      slotR[r] = slot;
    }
    float racc[16];
    #pragma unroll
    for (int r = 0; r < 16; ++r) racc[r] = 0.f;

    #pragma unroll 1
    for (int s = 0; s < ns; ++s) {
      const int T = T0 + s;
      const int need = s + 5;               // rounds -4..s complete
      for (;;) {
        const int v = *vprod;
        if ((v & 255) >= need && ((v >> 8) & 255) >= need &&
            ((v >> 16) & 255) >= need && ((v >> 24) & 255) >= need) break;
        __builtin_amdgcn_s_sleep(2);
      }
      __threadfence_block();

      const int tauW = T - 2 + wid;
      const int slot6 = (tauW + 12) % RING;
      const unsigned short* Ab = &Qsh[(T & 1) * 32 * LDSH + l31 * LDSH + hi * 8];
      const unsigned short* Bb = &Bsh[slot6 * 32 * LDSH + l31 * LDSH + hi * 8];
      f32x16 acc0 = {}, acc1 = {};
      __builtin_amdgcn_s_setprio(1);
      #pragma unroll
      for (int ks = 0; ks < 16; ks += 2) {
        const bf16x8 a0 = *reinterpret_cast<const bf16x8*>(Ab + ks * 16);
        const bf16x8 b0 = *reinterpret_cast<const bf16x8*>(Bb + ks * 16);
        const bf16x8 a1 = *reinterpret_cast<const bf16x8*>(Ab + ks * 16 + 16);
        const bf16x8 b1 = *reinterpret_cast<const bf16x8*>(Bb + ks * 16 + 16);
        acc0 = __builtin_amdgcn_mfma_f32_32x32x16_bf16(a0, b0, acc0, 0, 0, 0);
        acc1 = __builtin_amdgcn_mfma_f32_32x32x16_bf16(a1, b1, acc1, 0, 0, 0);
      }
      __builtin_amdgcn_s_setprio(0);

      const int bcol = tauW * 32 + l31;
      if (bcol >= 0 && bcol < N) {
        const float npW = NpS[slot6 * 32 + l31];
        const int aT = T * 32;
        #pragma unroll
        for (int r = 0; r < 16; ++r) {
          const int arow = (r & 3) + 8 * (r >> 2) + 4 * hi;
          if (slotR[r] >= 0 && (aT + arow) < N) {
            const float n2 = NqS[(T & 1) * 32 + arow] + npW
                             - 2.0f * (acc0[r] + acc1[r]);
            racc[r] += sqrtf(fmaxf(n2, 0.f));
          }
        }
      }

      __threadfence_block();                // frag reads retired before signal
      if (lane == 0) atomicAdd(&packs[1], 1 << (6 * wid));
    }

    // Once-per-block: registers -> LDS step slots.
    #pragma unroll
    for (int r = 0; r < 16; ++r)
      if (slotR[r] >= 0 && racc[r] != 0.f) atomicAdd(&sums[slotR[r]], racc[r]);
  }

  __syncthreads();
  if (t < S && t < MAXS) {
    const float v = sums[t];
    if (v != 0.f)
      unsafeAtomicAdd(&ws[(size_t)(blockIdx.x & (NREP - 1)) * MAXS + t], (double)v);
  }
}

__global__ void finalize_kernel(const double* __restrict__ ws, float* __restrict__ out,
                                const int* __restrict__ msp, const int* __restrict__ ssp,
                                int N) {
  __shared__ double dist_sh[MAXS];
  const int t = threadIdx.x;
  const int ms = msp[0], ss = ssp[0];
  const int S1 = (ms + ss - 1) / ss;
  const int S = 2 * S1;
  if (t < S && t < MAXS) {
    double tot = 0.0;
    for (int rep = 0; rep < NREP; ++rep) tot += ws[(size_t)rep * MAXS + t];
    tot += ws[(size_t)NREP * MAXS + t];   // corner pair
    const int k = (t < S1) ? t * ss : 1 + (t - S1) * ss;
    dist_sh[t] = tot / (double)(N - k);
  }
  __syncthreads();
  if (t == 0) {
    int best = 0;
    double bd = dist_sh[0];
    for (int s = 1; s < S && s < MAXS; ++s)
      if (dist_sh[s] < bd) { bd = dist_sh[s]; best = s; }
    const int k = (best < S1) ? best * ss : 1 + (best - S1) * ss;
    out[0] = (best < S1) ? (float)k : -(float)k;
    out[1] = (float)bd;
  }
}

extern "C" void kernel_launch(void* const* d_in, const int* in_sizes, int n_in,
                              void* d_out, int out_size, void* d_ws, size_t ws_size,
                              hipStream_t stream) {
  const float* Q   = (const float*)d_in[0];
  const float* P   = (const float*)d_in[1];
  const int*   msp = (const int*)d_in[2];
  const int*   ssp = (const int*)d_in[3];
  const int N = in_sizes[0] / 256;
  double* ws = (double*)d_ws;

  hipMemsetAsync(d_ws, 0, (size_t)(NREP + 1) * MAXS * sizeof(double), stream);

  const int TS = (N + 31) / 32;                 // total 32-row A-subtiles
  int nsb = (TS + 249) / 250;                   // subtiles per block (~13)
  if (nsb < 1) nsb = 1;
  if (nsb > 60) nsb = 60;                       // packed 6-bit counters cap
  const int gridB = (TS + nsb - 1) / nsb;       // ~241 band blocks, 1/CU

  band_kernel<<<gridB + MAXS, 576, 0, stream>>>(Q, P, ws, msp, ssp,
                                                N, TS, nsb, gridB);
  finalize_kernel<<<1, 128, 0, stream>>>(ws, (float*)d_out, msp, ssp, N);
}

// Round 15
// 61.673 us; speedup vs baseline: 1.8143x; 1.0075x over previous
//
#include <hip/hip_runtime.h>
#include <math.h>

// XYSearcher, sliding-window banded-GEMM, 32x32x16 MFMA,
// PRODUCER/CONSUMER wave specialization (no per-iteration barrier).
//   ||q_a - p_b||^2 = ||q_a||^2 + ||p_b||^2 - 2 q_a.p_b
// Integer steps: step k pairs rows at delta = a-b = +(k+1) [pos] / -(k+1)
// [neg]; one wrapped corner pair per step (fused corner blocks, exact fp32).
// Dots in bf16 MFMA, norms exact fp32 (absmax 0, rounds 3-8,11,14).
// 9 waves: waves 0-4 consume (ds frag reads + MFMA + epilogue), waves 5-8
// produce (global loads + fp32 norms + bf16 cvt + LDS ring writes).
// Protocol (verified r7/r14): round r stages Q[T0+r], P[T0+r+2]; consumer
// iter s needs prod fields >= s+5; producer round r needs cons fields >= r-1.
// ROUND-15 change (only): consumer fragment reads BATCHED into register
// arrays af[8]/bf[8] (16 ds_read_b128 in flight -> throughput-bound ~190cy
// instead of ~8 serial ~120cy latency exposures per iter; VGPR 68 gave the
// compiler ~4-fragment lookahead). __launch_bounds__(576,3) caps VGPR at 170
// so 3 waves/SIMD still fit (9 waves, 1 block/CU).

typedef __attribute__((ext_vector_type(8))) __bf16 bf16x8;
typedef __attribute__((ext_vector_type(16))) float f32x16;
typedef __attribute__((ext_vector_type(8))) unsigned short us8;

#define LDSH 280     // shorts per LDS row (560 B = 35 x 16B slots, conflict-free)
#define RING 6       // P ring slots
#define MAXS 128
#define NREP 32

__device__ __forceinline__ unsigned short f2bf(float x) {
  return __builtin_bit_cast(unsigned short, (__bf16)x);
}

__global__ __launch_bounds__(576, 3)
void band_kernel(const float* __restrict__ Q, const float* __restrict__ P,
                 double* __restrict__ ws,
                 const int* __restrict__ msp, const int* __restrict__ ssp,
                 int N, int TS, int nsb, int gridB) {
  __shared__ __align__(16) unsigned short Bsh[RING * 32 * LDSH];  // 105 KB
  __shared__ __align__(16) unsigned short Qsh[2 * 32 * LDSH];     // 35 KB
  __shared__ float NpS[RING * 32];
  __shared__ float NqS[2 * 32];
  __shared__ float sums[MAXS];
  __shared__ float red[12];
  __shared__ int packs[2];   // [0] prod (4 x 8-bit fields), [1] cons (5 x 6-bit)

  const int t = threadIdx.x;
  const int lane = t & 63;
  const int wid = t >> 6;          // 0..8
  const int ms = msp[0], ss = ssp[0];
  const int S1 = (ms + ss - 1) / ss;
  const int S = 2 * S1;

  // ---------------- fused corner blocks: one wrapped pair per step ---------
  if (blockIdx.x >= gridB) {
    const int si = blockIdx.x - gridB;
    if (si >= S) return;
    int k, qr, pr;
    if (si < S1) { k = si * ss;            qr = 0;           pr = N - (k + 1); }
    else         { k = 1 + (si - S1) * ss; qr = N - (k + 1); pr = 0; }
    float sq = 0.f;
    if (t < 256) {
      const float e = Q[(size_t)qr * 256 + t] - P[(size_t)pr * 256 + t];
      sq = e * e;
    }
    #pragma unroll
    for (int off = 32; off >= 1; off >>= 1) sq += __shfl_xor(sq, off);
    if (lane == 0) red[wid] = sq;
    __syncthreads();
    if (t == 0) {
      float tot = 0.f;
      #pragma unroll
      for (int w = 0; w < 9; ++w) tot += red[w];
      ws[(size_t)NREP * MAXS + si] = (double)sqrtf(tot);
    }
    return;
  }

  // ---------------- band blocks -------------------------------------------
  const int T0 = blockIdx.x * nsb;
  int ns = TS - T0; if (ns > nsb) ns = nsb;
  if (ns <= 0) return;

  for (int i = t; i < MAXS; i += 576) sums[i] = 0.f;
  if (t == 0) { packs[0] = 0; packs[1] = 0; }
  __syncthreads();

  volatile int* vprod = &packs[0];
  volatile int* vcons = &packs[1];

  if (wid >= 5) {
    // ================= PRODUCER waves (5..8) ==============================
    const int pw = wid - 5;              // 0..3: rows pw*8 .. pw*8+7 of each tile
    const int rr = pw * 8 + (lane >> 3); // tile-local row 0..31
    const int li = lane & 7;             // 8 lanes per row, 32 floats each

    float4 vp[8], vq[8];

    auto issueT = [&](const float* __restrict__ base, int tau, float4* v) {
      const int gr = tau * 32 + rr;
      if (gr >= 0 && gr < N) {
        const float* src = base + (size_t)gr * 256 + li * 8;
        #pragma unroll
        for (int j = 0; j < 4; ++j) {
          v[2 * j]     = *reinterpret_cast<const float4*>(src + j * 64);
          v[2 * j + 1] = *reinterpret_cast<const float4*>(src + j * 64 + 4);
        }
      } else {
        #pragma unroll
        for (int j = 0; j < 8; ++j) v[j] = make_float4(0.f, 0.f, 0.f, 0.f);
      }
    };

    auto commitT = [&](unsigned short* dst, float* ndst, int slot, const float4* v) {
      float nrm = 0.f;
      unsigned short* row = dst + slot * 32 * LDSH + rr * LDSH + li * 8;
      #pragma unroll
      for (int j = 0; j < 4; ++j) {
        const float f0 = v[2*j].x, f1 = v[2*j].y, f2 = v[2*j].z, f3 = v[2*j].w;
        const float f4 = v[2*j+1].x, f5 = v[2*j+1].y, f6 = v[2*j+1].z, f7 = v[2*j+1].w;
        nrm = fmaf(f0, f0, nrm); nrm = fmaf(f1, f1, nrm);
        nrm = fmaf(f2, f2, nrm); nrm = fmaf(f3, f3, nrm);
        nrm = fmaf(f4, f4, nrm); nrm = fmaf(f5, f5, nrm);
        nrm = fmaf(f6, f6, nrm); nrm = fmaf(f7, f7, nrm);
        us8 h;
        h[0] = f2bf(f0); h[1] = f2bf(f1); h[2] = f2bf(f2); h[3] = f2bf(f3);
        h[4] = f2bf(f4); h[5] = f2bf(f5); h[6] = f2bf(f6); h[7] = f2bf(f7);
        *reinterpret_cast<us8*>(row + j * 64) = h;
      }
      nrm += __shfl_xor(nrm, 1);
      nrm += __shfl_xor(nrm, 2);
      nrm += __shfl_xor(nrm, 4);
      if (li == 0) ndst[slot * 32 + rr] = nrm;   // exact fp32 row norm
    };

    #pragma unroll 1
    for (int r = -4; r < ns; ++r) {
      const int tauP = T0 + r + 2;
      const bool doQ = (r >= 0);
      issueT(P, tauP, vp);                  // loads in flight during the spin
      if (doQ) issueT(Q, T0 + r, vq);
      const int needc = r - 1;              // all consumers finished iter r-2
      if (needc > 0) {
        for (;;) {
          const int v = *vcons;
          if ((v & 63) >= needc && ((v >> 6) & 63) >= needc &&
              ((v >> 12) & 63) >= needc && ((v >> 18) & 63) >= needc &&
              ((v >> 24) & 63) >= needc) break;
          __builtin_amdgcn_s_sleep(2);
        }
      }
      commitT(Bsh, NpS, (tauP + 12) % RING, vp);
      if (doQ) commitT(Qsh, NqS, (T0 + r) & 1, vq);
      __threadfence_block();                // LDS writes visible before signal
      if (lane == 0) atomicAdd(&packs[0], 1 << (8 * pw));
    }
  } else {
    // ================= CONSUMER waves (0..4) ==============================
    const int l31 = lane & 31;
    const int hi = lane >> 5;

    // Per-thread step slots (T-invariant): delta = arow - l31 - (wid-2)*32.
    int slotR[16];
    #pragma unroll
    for (int r = 0; r < 16; ++r) {
      const int arow = (r & 3) + 8 * (r >> 2) + 4 * hi;
      const int d = arow - l31 - (wid - 2) * 32;
      int slot = -1;
      if (d >= 1) {
        const int k = d - 1;
        if (k < ms && (k % ss) == 0) slot = k / ss;
      } else if (d <= -2) {
        const int kk = -d - 1;
        if (kk <= ms && ((kk - 1) % ss) == 0) slot = S1 + (kk - 1) / ss;
      }
      if (slot >= MAXS) slot = -1;
      slotR[r] = slot;
    }
    float racc[16];
    #pragma unroll
    for (int r = 0; r < 16; ++r) racc[r] = 0.f;

    #pragma unroll 1
    for (int s = 0; s < ns; ++s) {
      const int T = T0 + s;
      const int need = s + 5;               // rounds -4..s complete
      for (;;) {
        const int v = *vprod;
        if ((v & 255) >= need && ((v >> 8) & 255) >= need &&
            ((v >> 16) & 255) >= need && ((v >> 24) & 255) >= need) break;
        __builtin_amdgcn_s_sleep(2);
      }
      __threadfence_block();

      const int tauW = T - 2 + wid;
      const int slot6 = (tauW + 12) % RING;
      const unsigned short* Ab = &Qsh[(T & 1) * 32 * LDSH + l31 * LDSH + hi * 8];
      const unsigned short* Bb = &Bsh[slot6 * 32 * LDSH + l31 * LDSH + hi * 8];
      f32x16 acc0 = {}, acc1 = {};

      // ---- Batch 16 ds_read_b128 into registers, then 8 MFMAs; x2.
      bf16x8 af[8], bf[8];
      #pragma unroll
      for (int ks = 0; ks < 8; ++ks) {
        af[ks] = *reinterpret_cast<const bf16x8*>(Ab + ks * 16);
        bf[ks] = *reinterpret_cast<const bf16x8*>(Bb + ks * 16);
      }
      __builtin_amdgcn_s_setprio(1);
      #pragma unroll
      for (int ks = 0; ks < 8; ks += 2) {
        acc0 = __builtin_amdgcn_mfma_f32_32x32x16_bf16(af[ks],     bf[ks],     acc0, 0, 0, 0);
        acc1 = __builtin_amdgcn_mfma_f32_32x32x16_bf16(af[ks + 1], bf[ks + 1], acc1, 0, 0, 0);
      }
      __builtin_amdgcn_s_setprio(0);
      #pragma unroll
      for (int ks = 0; ks < 8; ++ks) {
        af[ks] = *reinterpret_cast<const bf16x8*>(Ab + (ks + 8) * 16);
        bf[ks] = *reinterpret_cast<const bf16x8*>(Bb + (ks + 8) * 16);
      }
      __builtin_amdgcn_s_setprio(1);
      #pragma unroll
      for (int ks = 0; ks < 8; ks += 2) {
        acc0 = __builtin_amdgcn_mfma_f32_32x32x16_bf16(af[ks],     bf[ks],     acc0, 0, 0, 0);
        acc1 = __builtin_amdgcn_mfma_f32_32x32x16_bf16(af[ks + 1], bf[ks + 1], acc1, 0, 0, 0);
      }
      __builtin_amdgcn_s_setprio(0);

      const int bcol = tauW * 32 + l31;
      if (bcol >= 0 && bcol < N) {
        const float npW = NpS[slot6 * 32 + l31];
        const int aT = T * 32;
        #pragma unroll
        for (int r = 0; r < 16; ++r) {
          const int arow = (r & 3) + 8 * (r >> 2) + 4 * hi;
          if (slotR[r] >= 0 && (aT + arow) < N) {
            const float n2 = NqS[(T & 1) * 32 + arow] + npW
                             - 2.0f * (acc0[r] + acc1[r]);
            racc[r] += sqrtf(fmaxf(n2, 0.f));
          }
        }
      }

      __threadfence_block();                // frag reads retired before signal
      if (lane == 0) atomicAdd(&packs[1], 1 << (6 * wid));
    }

    // Once-per-block: registers -> LDS step slots.
    #pragma unroll
    for (int r = 0; r < 16; ++r)
      if (slotR[r] >= 0 && racc[r] != 0.f) atomicAdd(&sums[slotR[r]], racc[r]);
  }

  __syncthreads();
  if (t < S && t < MAXS) {
    const float v = sums[t];
    if (v != 0.f)
      unsafeAtomicAdd(&ws[(size_t)(blockIdx.x & (NREP - 1)) * MAXS + t], (double)v);
  }
}

__global__ void finalize_kernel(const double* __restrict__ ws, float* __restrict__ out,
                                const int* __restrict__ msp, const int* __restrict__ ssp,
                                int N) {
  __shared__ double dist_sh[MAXS];
  const int t = threadIdx.x;
  const int ms = msp[0], ss = ssp[0];
  const int S1 = (ms + ss - 1) / ss;
  const int S = 2 * S1;
  if (t < S && t < MAXS) {
    double tot = 0.0;
    for (int rep = 0; rep < NREP; ++rep) tot += ws[(size_t)rep * MAXS + t];
    tot += ws[(size_t)NREP * MAXS + t];   // corner pair
    const int k = (t < S1) ? t * ss : 1 + (t - S1) * ss;
    dist_sh[t] = tot / (double)(N - k);
  }
  __syncthreads();
  if (t == 0) {
    int best = 0;
    double bd = dist_sh[0];
    for (int s = 1; s < S && s < MAXS; ++s)
      if (dist_sh[s] < bd) { bd = dist_sh[s]; best = s; }
    const int k = (best < S1) ? best * ss : 1 + (best - S1) * ss;
    out[0] = (best < S1) ? (float)k : -(float)k;
    out[1] = (float)bd;
  }
}

extern "C" void kernel_launch(void* const* d_in, const int* in_sizes, int n_in,
                              void* d_out, int out_size, void* d_ws, size_t ws_size,
                              hipStream_t stream) {
  const float* Q   = (const float*)d_in[0];
  const float* P   = (const float*)d_in[1];
  const int*   msp = (const int*)d_in[2];
  const int*   ssp = (const int*)d_in[3];
  const int N = in_sizes[0] / 256;
  double* ws = (double*)d_ws;

  hipMemsetAsync(d_ws, 0, (size_t)(NREP + 1) * MAXS * sizeof(double), stream);

  const int TS = (N + 31) / 32;                 // total 32-row A-subtiles
  int nsb = (TS + 249) / 250;                   // subtiles per block (~13)
  if (nsb < 1) nsb = 1;
  if (nsb > 60) nsb = 60;                       // packed 6-bit counters cap
  const int gridB = (TS + nsb - 1) / nsb;       // ~241 band blocks, 1/CU

  band_kernel<<<gridB + MAXS, 576, 0, stream>>>(Q, P, ws, msp, ssp,
                                                N, TS, nsb, gridB);
  finalize_kernel<<<1, 128, 0, stream>>>(ws, (float*)d_out, msp, ssp, N);
}